// Round 5
// baseline (195.494 us; speedup 1.0000x reference)
//
#include <hip/hip_runtime.h>
#include <math.h>

#define B_  4
#define C_  256
#define CI_ 128
#define N_  4096
#define D_  128
#define KVSPLIT 4
#define KVQ  (N_ / KVSPLIT)

typedef short bf16x8 __attribute__((ext_vector_type(8)));
typedef float f32x4 __attribute__((ext_vector_type(4)));
typedef unsigned short u16;

__device__ __forceinline__ u16 f2bf(float x) {
    union { float f; unsigned u; } v; v.f = x;
    unsigned r = v.u + 0x7FFFu + ((v.u >> 16) & 1u);
    return (u16)(r >> 16);
}
__device__ __forceinline__ float bf2f(u16 u) {
    union { unsigned u; float f; } v; v.u = ((unsigned)u) << 16; return v.f;
}
__device__ __forceinline__ unsigned pack2(float a, float b) {
    return (unsigned)f2bf(a) | ((unsigned)f2bf(b) << 16);
}

// ---------------------------------------------------------------------------
// Embedding conv1x1 as hi/lo bf16 MFMA GEMM.  (unchanged from round 4)
// ---------------------------------------------------------------------------
__global__ __launch_bounds__(256) void embed_kernel(
    const float* __restrict__ x, const float* __restrict__ src,
    const float* __restrict__ g_w, const float* __restrict__ g_b,
    const float* __restrict__ th_w, const float* __restrict__ th_b,
    const float* __restrict__ ph_w, const float* __restrict__ ph_b,
    u16* __restrict__ th_hi, u16* __restrict__ th_lo,
    u16* __restrict__ ph_hi, u16* __restrict__ ph_lo,
    u16* __restrict__ gt)
{
    __shared__ u16 xh[64 * 40];
    __shared__ u16 xl[64 * 40];

    const int n0 = blockIdx.x * 64, b = blockIdx.y, which = blockIdx.z;
    const float *in, *wm, *bias;
    if (which == 0)      { in = x;   wm = th_w; bias = th_b; }
    else if (which == 1) { in = src; wm = ph_w; bias = ph_b; }
    else                 { in = src; wm = g_w;  bias = g_b;  }

    const int t = threadIdx.x, lane = t & 63, wv = t >> 6;
    const int lq = lane & 15, lh = lane >> 4;
    const int mf0 = wv * 2;

    f32x4 acc[2][4];
#pragma unroll
    for (int m = 0; m < 2; ++m) {
        float b0 = bias[16 * (mf0 + m) + 4 * lh + 0];
        float b1 = bias[16 * (mf0 + m) + 4 * lh + 1];
        float b2 = bias[16 * (mf0 + m) + 4 * lh + 2];
        float b3 = bias[16 * (mf0 + m) + 4 * lh + 3];
#pragma unroll
        for (int s = 0; s < 4; ++s) acc[m][s] = (f32x4){b0, b1, b2, b3};
    }

    const float* colbase = in + (size_t)b * C_ * N_ + n0;
    const int cq = t >> 6;

    for (int k = 0; k < 8; ++k) {
        const int c0 = k * 32;
        __syncthreads();
#pragma unroll
        for (int p = 0; p < 2; ++p) {
            int cl = 16 * p + 4 * cq;
            float v0 = colbase[(size_t)(c0 + cl + 0) * N_ + lane];
            float v1 = colbase[(size_t)(c0 + cl + 1) * N_ + lane];
            float v2 = colbase[(size_t)(c0 + cl + 2) * N_ + lane];
            float v3 = colbase[(size_t)(c0 + cl + 3) * N_ + lane];
            u16 h0 = f2bf(v0), h1 = f2bf(v1), h2 = f2bf(v2), h3 = f2bf(v3);
            ushort4 hv = {h0, h1, h2, h3};
            ushort4 lv = {f2bf(v0 - bf2f(h0)), f2bf(v1 - bf2f(h1)),
                          f2bf(v2 - bf2f(h2)), f2bf(v3 - bf2f(h3))};
            *(ushort4*)&xh[lane * 40 + cl] = hv;
            *(ushort4*)&xl[lane * 40 + cl] = lv;
        }
        __syncthreads();

        bf16x8 wh[2], wl[2];
#pragma unroll
        for (int m = 0; m < 2; ++m) {
            const float* wp = wm + (size_t)(16 * (mf0 + m) + lq) * C_ + c0 + 8 * lh;
            float4 a = *(const float4*)wp;
            float4 bq = *(const float4*)(wp + 4);
            float wf[8] = {a.x, a.y, a.z, a.w, bq.x, bq.y, bq.z, bq.w};
#pragma unroll
            for (int j = 0; j < 8; ++j) {
                u16 h = f2bf(wf[j]);
                wh[m][j] = (short)h;
                wl[m][j] = (short)f2bf(wf[j] - bf2f(h));
            }
        }
#pragma unroll
        for (int s = 0; s < 4; ++s) {
            bf16x8 xhf = *(const bf16x8*)&xh[(16 * s + lq) * 40 + 8 * lh];
            bf16x8 xlf = *(const bf16x8*)&xl[(16 * s + lq) * 40 + 8 * lh];
#pragma unroll
            for (int m = 0; m < 2; ++m) {
                acc[m][s] = __builtin_amdgcn_mfma_f32_16x16x32_bf16(wh[m], xhf, acc[m][s], 0, 0, 0);
                acc[m][s] = __builtin_amdgcn_mfma_f32_16x16x32_bf16(wl[m], xhf, acc[m][s], 0, 0, 0);
                acc[m][s] = __builtin_amdgcn_mfma_f32_16x16x32_bf16(wh[m], xlf, acc[m][s], 0, 0, 0);
            }
        }
    }

    if (which < 2) {
        u16* oh = (which == 0 ? th_hi : ph_hi) + (size_t)b * N_ * CI_;
        u16* ol = (which == 0 ? th_lo : ph_lo) + (size_t)b * N_ * CI_;
#pragma unroll
        for (int m = 0; m < 2; ++m)
#pragma unroll
            for (int s = 0; s < 4; ++s) {
                ushort4 hv, lv;
                u16 h;
                h = f2bf(acc[m][s][0]); hv.x = h; lv.x = f2bf(acc[m][s][0] - bf2f(h));
                h = f2bf(acc[m][s][1]); hv.y = h; lv.y = f2bf(acc[m][s][1] - bf2f(h));
                h = f2bf(acc[m][s][2]); hv.z = h; lv.z = f2bf(acc[m][s][2] - bf2f(h));
                h = f2bf(acc[m][s][3]); hv.w = h; lv.w = f2bf(acc[m][s][3] - bf2f(h));
                size_t ofs = (size_t)(n0 + 16 * s + lq) * CI_ + 16 * (mf0 + m) + 4 * lh;
                *(ushort4*)(oh + ofs) = hv;
                *(ushort4*)(ol + ofs) = lv;
            }
    } else {
        u16* gb = gt + (size_t)b * CI_ * N_;
#pragma unroll
        for (int m = 0; m < 2; ++m)
#pragma unroll
            for (int s = 0; s < 4; ++s)
#pragma unroll
                for (int r = 0; r < 4; ++r)
                    gb[(size_t)(16 * (mf0 + m) + 4 * lh + r) * N_ + n0 + 16 * s + lq] =
                        f2bf(acc[m][s][r]);
    }
}

// ---------------------------------------------------------------------------
// Flash attention: swapped-operand MFMA, 32 q per wave, kv-split x4.
// grid (N/128, B, 4), block 256 (4 waves x 32 q).  LDS 48KB.
// S^T = mfma(K, Q): lane holds S(q=lq, kv=16tt+4lh+r) per q-subtile.
// P redistribution to PV B-operand layout via 8 __shfl (no LDS).
// PV: O^T = mfma(Vt_row, pf): lane holds O(q=lq, d=16j+4lh+r).
// Partials (unnormalized O bf16, m/l f32) merged by merge_kernel.
// ---------------------------------------------------------------------------
__global__ __launch_bounds__(256, 2) void attn_kernel(
    const u16* __restrict__ th_hi, const u16* __restrict__ th_lo,
    const u16* __restrict__ ph_hi, const u16* __restrict__ ph_lo,
    const u16* __restrict__ gt, u16* __restrict__ part, float* __restrict__ ml)
{
    __shared__ u16 Ksh[64 * 128];
    __shared__ u16 Ksl[64 * 128];
    __shared__ u16 Vt[128 * 64];

    const int n0 = blockIdx.x * 128, b = blockIdx.y, sp = blockIdx.z;
    const int t = threadIdx.x, wv = t >> 6, lane = t & 63;
    const int lq = lane & 15, lh = lane >> 4;
    const int par = lh & 1, flip = lh >> 1;
    const int q0w = n0 + wv * 32;

    bf16x8 qfh[2][4], qfl[2][4];
#pragma unroll
    for (int qs = 0; qs < 2; ++qs) {
        const u16* qph = th_hi + ((size_t)b * N_ + q0w + 16 * qs + lq) * D_ + 8 * lh;
        const u16* qpl = th_lo + ((size_t)b * N_ + q0w + 16 * qs + lq) * D_ + 8 * lh;
#pragma unroll
        for (int c = 0; c < 4; ++c) {
            qfh[qs][c] = *(const bf16x8*)(qph + 32 * c);
            qfl[qs][c] = *(const bf16x8*)(qpl + 32 * c);
        }
    }

    f32x4 Ot[2][8];
#pragma unroll
    for (int qs = 0; qs < 2; ++qs)
#pragma unroll
        for (int j = 0; j < 8; ++j) Ot[qs][j] = (f32x4){0.f, 0.f, 0.f, 0.f};
    float m_run[2] = {-INFINITY, -INFINITY};
    float l_run[2] = {0.f, 0.f};

    const u16* kbh = ph_hi + ((size_t)b * N_ + (size_t)sp * KVQ) * D_;
    const u16* kbl = ph_lo + ((size_t)b * N_ + (size_t)sp * KVQ) * D_;
    const u16* vb  = gt + (size_t)b * D_ * N_ + sp * KVQ;

    for (int kv0 = 0; kv0 < KVQ; kv0 += 64) {
        __syncthreads();
        {
            int r = t >> 4, d0 = (t & 15) * 8;
#pragma unroll
            for (int i = 0; i < 4; ++i) {
                int rr = r + 16 * i;
                int off = rr * 128 + (d0 ^ ((rr & 7) << 3));
                *(bf16x8*)&Ksh[off] = *(const bf16x8*)(kbh + (size_t)(kv0 + rr) * D_ + d0);
                *(bf16x8*)&Ksl[off] = *(const bf16x8*)(kbl + (size_t)(kv0 + rr) * D_ + d0);
            }
            int d = t >> 3, k8 = (t & 7) * 8;
#pragma unroll
            for (int i = 0; i < 4; ++i) {
                int dd = d + 32 * i;
                *(bf16x8*)&Vt[dd * 64 + (k8 ^ ((dd & 7) << 3))] =
                    *(const bf16x8*)(vb + (size_t)dd * N_ + kv0 + k8);
            }
        }
        __syncthreads();

        // ---- S^T = K Q^T (hi/lo 3-term), both q-subtiles per K-read ----
        f32x4 S[2][4];
#pragma unroll
        for (int qs = 0; qs < 2; ++qs)
#pragma unroll
            for (int tt = 0; tt < 4; ++tt) S[qs][tt] = (f32x4){0.f, 0.f, 0.f, 0.f};
#pragma unroll
        for (int c = 0; c < 4; ++c)
#pragma unroll
            for (int tt = 0; tt < 4; ++tt) {
                int row = 16 * tt + lq;
                int off = row * 128 + ((32 * c + 8 * lh) ^ ((row & 7) << 3));
                bf16x8 kh = *(const bf16x8*)&Ksh[off];
                bf16x8 kl = *(const bf16x8*)&Ksl[off];
#pragma unroll
                for (int qs = 0; qs < 2; ++qs) {
                    S[qs][tt] = __builtin_amdgcn_mfma_f32_16x16x32_bf16(kh, qfh[qs][c], S[qs][tt], 0, 0, 0);
                    S[qs][tt] = __builtin_amdgcn_mfma_f32_16x16x32_bf16(kh, qfl[qs][c], S[qs][tt], 0, 0, 0);
                    S[qs][tt] = __builtin_amdgcn_mfma_f32_16x16x32_bf16(kl, qfh[qs][c], S[qs][tt], 0, 0, 0);
                }
            }

        // ---- softmax + P redistribution (register-only, per q-subtile) ----
        bf16x8 pf[2][2];
#pragma unroll
        for (int qs = 0; qs < 2; ++qs) {
            float mx = -INFINITY;
#pragma unroll
            for (int tt = 0; tt < 4; ++tt)
#pragma unroll
                for (int r = 0; r < 4; ++r) mx = fmaxf(mx, S[qs][tt][r]);
            mx = fmaxf(mx, __shfl_xor(mx, 16));
            mx = fmaxf(mx, __shfl_xor(mx, 32));
            float mn = fmaxf(m_run[qs], mx);
            float al = __expf(m_run[qs] - mn);
            m_run[qs] = mn;
            float p[4][4];
            float ls = 0.f;
#pragma unroll
            for (int tt = 0; tt < 4; ++tt)
#pragma unroll
                for (int r = 0; r < 4; ++r) {
                    p[tt][r] = __expf(S[qs][tt][r] - mn);
                    ls += p[tt][r];
                }
            ls += __shfl_xor(ls, 16);
            ls += __shfl_xor(ls, 32);
            l_run[qs] = l_run[qs] * al + ls;
#pragma unroll
            for (int j = 0; j < 8; ++j) Ot[qs][j] *= al;

            // pack own bf16 pairs: wloc[2tt+(r>>1)] covers kv = 16tt+4lh+2(r>>1)+{0,1}
            unsigned wloc[8];
#pragma unroll
            for (int tt = 0; tt < 4; ++tt) {
                wloc[2 * tt]     = pack2(p[tt][0], p[tt][1]);
                wloc[2 * tt + 1] = pack2(p[tt][2], p[tt][3]);
            }
            // 8 exchange ops within the 4-lane group {lq, lq+16, lq+32, lq+48}
            unsigned rcv[8];
#pragma unroll
            for (int k = 0; k < 8; ++k) {
                const int idx = k & 3;
                const int wL = ((idx >> 1) << 2) | (idx & 1);   // L = {0,1,4,5}
                unsigned snd = (par ^ (k >> 2)) ? wloc[wL + 2] : wloc[wL];
                int srcl = lq + 32 * par + 16 * ((k >> 2) ^ flip);
                rcv[k] = (unsigned)__shfl((int)snd, srcl);
            }
            // out[cc][u] = P pairs at kv = 32cc + 8lh + 2u (+1)
#pragma unroll
            for (int cc = 0; cc < 2; ++cc) {
                union { unsigned w[4]; bf16x8 v; } pu;
#pragma unroll
                for (int u = 0; u < 4; ++u) {
                    unsigned a  = rcv[4 * (u >> 1)       + 2 * cc + (u & 1)];
                    unsigned bb = rcv[4 * (1 - (u >> 1)) + 2 * cc + (u & 1)];
                    pu.w[u] = flip ? bb : a;
                }
                pf[qs][cc] = pu.v;
            }
        }

        // ---- O^T += V^T P^T : one V-read feeds both q-subtiles ----
#pragma unroll
        for (int cc = 0; cc < 2; ++cc)
#pragma unroll
            for (int j = 0; j < 8; ++j) {
                int row = 16 * j + lq;
                bf16x8 vf = *(const bf16x8*)&Vt[row * 64 + ((32 * cc + 8 * lh) ^ ((row & 7) << 3))];
                Ot[0][j] = __builtin_amdgcn_mfma_f32_16x16x32_bf16(vf, pf[0][cc], Ot[0][j], 0, 0, 0);
                Ot[1][j] = __builtin_amdgcn_mfma_f32_16x16x32_bf16(vf, pf[1][cc], Ot[1][j], 0, 0, 0);
            }
    }

    // ---- partial store: part[sp][b][q][d] bf16, ml[sp][b][q] = {m,l} ----
#pragma unroll
    for (int qs = 0; qs < 2; ++qs) {
        u16* pb = part + (((size_t)sp * B_ + b) * N_ + q0w + 16 * qs + lq) * D_;
#pragma unroll
        for (int j = 0; j < 8; ++j) {
            ushort4 pk = {f2bf(Ot[qs][j][0]), f2bf(Ot[qs][j][1]),
                          f2bf(Ot[qs][j][2]), f2bf(Ot[qs][j][3])};
            *(ushort4*)(pb + 16 * j + 4 * lh) = pk;
        }
        if (lh == 0) {
            float* mp = ml + ((((size_t)sp * B_ + b) * N_) + q0w + 16 * qs + lq) * 2;
            mp[0] = m_run[qs];
            mp[1] = l_run[qs];
        }
    }
}

// ---------------------------------------------------------------------------
// Merge 4 kv-split partials -> y[b][n][ci] bf16.  grid (N/64, B), block 256.
// ---------------------------------------------------------------------------
__global__ __launch_bounds__(256) void merge_kernel(
    const u16* __restrict__ part, const float* __restrict__ ml,
    u16* __restrict__ y)
{
    const int n0 = blockIdx.x * 64, b = blockIdx.y;
    const int t = threadIdx.x;
#pragma unroll
    for (int i = 0; i < 4; ++i) {
        int item = i * 256 + t;
        int q = n0 + (item >> 4), s8 = (item & 15) * 8;
        float2 mls[KVSPLIT];
        float m = -INFINITY;
#pragma unroll
        for (int s = 0; s < KVSPLIT; ++s) {
            mls[s] = *(const float2*)(ml + (((size_t)s * B_ + b) * N_ + q) * 2);
            m = fmaxf(m, mls[s].x);
        }
        float w[KVSPLIT];
        float denom = 0.f;
#pragma unroll
        for (int s = 0; s < KVSPLIT; ++s) {
            w[s] = __expf(mls[s].x - m);
            denom += w[s] * mls[s].y;
        }
        float inv = 1.f / denom;
        float acc[8];
#pragma unroll
        for (int e = 0; e < 8; ++e) acc[e] = 0.f;
#pragma unroll
        for (int s = 0; s < KVSPLIT; ++s) {
            bf16x8 o = *(const bf16x8*)(part + (((size_t)s * B_ + b) * N_ + q) * D_ + s8);
#pragma unroll
            for (int e = 0; e < 8; ++e) acc[e] += w[s] * bf2f((u16)o[e]);
        }
        bf16x8 ov;
#pragma unroll
        for (int e = 0; e < 8; ++e) ov[e] = (short)f2bf(acc[e] * inv);
        *(bf16x8*)(y + ((size_t)b * N_ + q) * CI_ + s8) = ov;
    }
}

// ---------------------------------------------------------------------------
// Wz conv1x1 (MFMA) + BN partial sums.  (unchanged from round 4)
// ---------------------------------------------------------------------------
__global__ __launch_bounds__(256) void wz_kernel(
    const u16* __restrict__ y, const float* __restrict__ wz_w,
    const float* __restrict__ wz_b, float* __restrict__ w_y,
    float* __restrict__ sums)
{
    __shared__ u16 ylds[64 * 128];
    const int n0 = blockIdx.x * 64, b = blockIdx.y;
    const int t = threadIdx.x, lane = t & 63, wv = t >> 6;
    const int lq = lane & 15, lh = lane >> 4;

#pragma unroll
    for (int i = 0; i < 4; ++i) {
        int flat = i * 256 + t;
        int row = flat >> 4, s = flat & 15;
        bf16x8 v = *(const bf16x8*)(y + ((size_t)(b * N_ + n0 + row)) * CI_ + 8 * s);
        *(bf16x8*)&ylds[row * 128 + 8 * (s ^ (row & 7))] = v;
    }
    __syncthreads();

    f32x4 acc[4][4];
#pragma unroll
    for (int mm = 0; mm < 4; ++mm) {
        float b0 = wz_b[16 * (4 * wv + mm) + 4 * lh + 0];
        float b1 = wz_b[16 * (4 * wv + mm) + 4 * lh + 1];
        float b2 = wz_b[16 * (4 * wv + mm) + 4 * lh + 2];
        float b3 = wz_b[16 * (4 * wv + mm) + 4 * lh + 3];
#pragma unroll
        for (int s = 0; s < 4; ++s) acc[mm][s] = (f32x4){b0, b1, b2, b3};
    }

#pragma unroll
    for (int k = 0; k < 4; ++k) {
        bf16x8 wf[4];
#pragma unroll
        for (int mm = 0; mm < 4; ++mm) {
            const float* wp = wz_w + (size_t)(16 * (4 * wv + mm) + lq) * CI_ + 32 * k + 8 * lh;
            float4 a = *(const float4*)wp;
            float4 bq = *(const float4*)(wp + 4);
            wf[mm][0] = (short)f2bf(a.x);  wf[mm][1] = (short)f2bf(a.y);
            wf[mm][2] = (short)f2bf(a.z);  wf[mm][3] = (short)f2bf(a.w);
            wf[mm][4] = (short)f2bf(bq.x); wf[mm][5] = (short)f2bf(bq.y);
            wf[mm][6] = (short)f2bf(bq.z); wf[mm][7] = (short)f2bf(bq.w);
        }
#pragma unroll
        for (int s = 0; s < 4; ++s) {
            int row = 16 * s + lq;
            bf16x8 yf = *(const bf16x8*)&ylds[row * 128 + 8 * ((4 * k + lh) ^ (row & 7))];
#pragma unroll
            for (int mm = 0; mm < 4; ++mm)
                acc[mm][s] = __builtin_amdgcn_mfma_f32_16x16x32_bf16(wf[mm], yf, acc[mm][s], 0, 0, 0);
        }
    }

#pragma unroll
    for (int mm = 0; mm < 4; ++mm) {
        int cb = 16 * (4 * wv + mm) + 4 * lh;
#pragma unroll
        for (int s = 0; s < 4; ++s) {
            int n = n0 + 16 * s + lq;
#pragma unroll
            for (int r = 0; r < 4; ++r)
                w_y[((size_t)b * C_ + cb + r) * N_ + n] = acc[mm][s][r];
        }
#pragma unroll
        for (int r = 0; r < 4; ++r) {
            float sv = acc[mm][0][r] + acc[mm][1][r] + acc[mm][2][r] + acc[mm][3][r];
            float qv = acc[mm][0][r] * acc[mm][0][r] + acc[mm][1][r] * acc[mm][1][r]
                     + acc[mm][2][r] * acc[mm][2][r] + acc[mm][3][r] * acc[mm][3][r];
#pragma unroll
            for (int d = 1; d < 16; d <<= 1) {
                sv += __shfl_xor(sv, d);
                qv += __shfl_xor(qv, d);
            }
            if (lq == 0) {
                atomicAdd(&sums[cb + r], sv);
                atomicAdd(&sums[C_ + cb + r], qv);
            }
        }
    }
}

// ---------------------------------------------------------------------------
// BN finalize + residual  (unchanged)
// ---------------------------------------------------------------------------
__global__ __launch_bounds__(256) void final_kernel(
    const float* __restrict__ w_y, const float* __restrict__ src,
    const float* __restrict__ gamma, const float* __restrict__ beta,
    const float* __restrict__ sums, float* __restrict__ out)
{
    const float invN = 1.0f / (float)(B_ * N_);
    const size_t tot4 = (size_t)B_ * C_ * N_ / 4;
    size_t stride = (size_t)gridDim.x * blockDim.x;
    for (size_t i4 = (size_t)blockIdx.x * blockDim.x + threadIdx.x; i4 < tot4; i4 += stride) {
        size_t i = i4 * 4;
        int c = (int)((i / N_) % C_);
        float mean  = sums[c] * invN;
        float var   = sums[C_ + c] * invN - mean * mean;
        float scale = rsqrtf(var + 1e-5f) * gamma[c];
        float bb    = beta[c];
        float4 w = *(const float4*)(w_y + i);
        float4 s = *(const float4*)(src + i);
        float4 o;
        o.x = (w.x - mean) * scale + bb + s.x;
        o.y = (w.y - mean) * scale + bb + s.y;
        o.z = (w.z - mean) * scale + bb + s.z;
        o.w = (w.w - mean) * scale + bb + s.w;
        *(float4*)((float*)out + i) = o;
    }
}

extern "C" void kernel_launch(void* const* d_in, const int* in_sizes, int n_in,
                              void* d_out, int out_size, void* d_ws, size_t ws_size,
                              hipStream_t stream)
{
    const float* x     = (const float*)d_in[0];
    const float* src   = (const float*)d_in[1];
    const float* g_w   = (const float*)d_in[2];
    const float* g_b   = (const float*)d_in[3];
    const float* th_w  = (const float*)d_in[4];
    const float* th_b  = (const float*)d_in[5];
    const float* ph_w  = (const float*)d_in[6];
    const float* ph_b  = (const float*)d_in[7];
    const float* wz_w  = (const float*)d_in[8];
    const float* wz_b  = (const float*)d_in[9];
    const float* gamma = (const float*)d_in[10];
    const float* beta  = (const float*)d_in[11];

    char* ws = (char*)d_ws;
    u16*   th_hi = (u16*)(ws + (0u  << 20));    //  4 MB
    u16*   th_lo = (u16*)(ws + (4u  << 20));    //  4 MB
    u16*   ph_hi = (u16*)(ws + (8u  << 20));    //  4 MB
    u16*   ph_lo = (u16*)(ws + (12u << 20));    //  4 MB
    u16*   gt    = (u16*)(ws + (16u << 20));    //  4 MB
    u16*   part  = (u16*)(ws + (20u << 20));    // 16 MB [4][B][N][D] bf16
    float* mlbuf = (float*)(ws + (36u << 20));  // 512 KB [4][B][N][2]
    u16*   y     = (u16*)(ws + (0u  << 20));    //  4 MB, aliases th_hi (dead)
    float* w_y   = (float*)(ws + (20u << 20));  // 16 MB, aliases part (dead)
    float* sums  = (float*)(ws + (36u << 20) + (1u << 19)); // 2 KB

    hipMemsetAsync(sums, 0, 2 * C_ * sizeof(float), stream);

    embed_kernel<<<dim3(64, 4, 3), 256, 0, stream>>>(
        x, src, g_w, g_b, th_w, th_b, ph_w, ph_b,
        th_hi, th_lo, ph_hi, ph_lo, gt);
    attn_kernel<<<dim3(N_ / 128, B_, KVSPLIT), 256, 0, stream>>>(
        th_hi, th_lo, ph_hi, ph_lo, gt, part, mlbuf);
    merge_kernel<<<dim3(64, 4), 256, 0, stream>>>(part, mlbuf, y);
    wz_kernel<<<dim3(64, 4), 256, 0, stream>>>(y, wz_w, wz_b, w_y, sums);
    final_kernel<<<2048, 256, 0, stream>>>(w_y, src, gamma, beta, sums, (float*)d_out);
}

// Round 6
// 195.231 us; speedup vs baseline: 1.0013x; 1.0013x over previous
//
#include <hip/hip_runtime.h>
#include <math.h>

#define B_  4
#define C_  256
#define CI_ 128
#define N_  4096
#define D_  128
#define KVSPLIT 4
#define KVQ  (N_ / KVSPLIT)

typedef short bf16x8 __attribute__((ext_vector_type(8)));
typedef float f32x4 __attribute__((ext_vector_type(4)));
typedef unsigned short u16;

__device__ __forceinline__ u16 f2bf(float x) {
    union { float f; unsigned u; } v; v.f = x;
    unsigned r = v.u + 0x7FFFu + ((v.u >> 16) & 1u);
    return (u16)(r >> 16);
}
__device__ __forceinline__ float bf2f(u16 u) {
    union { unsigned u; float f; } v; v.u = ((unsigned)u) << 16; return v.f;
}
__device__ __forceinline__ unsigned pack2(float a, float b) {
    return (unsigned)f2bf(a) | ((unsigned)f2bf(b) << 16);
}

// ---------------------------------------------------------------------------
// Embedding conv1x1 as hi/lo bf16 MFMA GEMM.  (unchanged from round 4)
// ---------------------------------------------------------------------------
__global__ __launch_bounds__(256) void embed_kernel(
    const float* __restrict__ x, const float* __restrict__ src,
    const float* __restrict__ g_w, const float* __restrict__ g_b,
    const float* __restrict__ th_w, const float* __restrict__ th_b,
    const float* __restrict__ ph_w, const float* __restrict__ ph_b,
    u16* __restrict__ th_hi, u16* __restrict__ th_lo,
    u16* __restrict__ ph_hi, u16* __restrict__ ph_lo,
    u16* __restrict__ gt)
{
    __shared__ u16 xh[64 * 40];
    __shared__ u16 xl[64 * 40];

    const int n0 = blockIdx.x * 64, b = blockIdx.y, which = blockIdx.z;
    const float *in, *wm, *bias;
    if (which == 0)      { in = x;   wm = th_w; bias = th_b; }
    else if (which == 1) { in = src; wm = ph_w; bias = ph_b; }
    else                 { in = src; wm = g_w;  bias = g_b;  }

    const int t = threadIdx.x, lane = t & 63, wv = t >> 6;
    const int lq = lane & 15, lh = lane >> 4;
    const int mf0 = wv * 2;

    f32x4 acc[2][4];
#pragma unroll
    for (int m = 0; m < 2; ++m) {
        float b0 = bias[16 * (mf0 + m) + 4 * lh + 0];
        float b1 = bias[16 * (mf0 + m) + 4 * lh + 1];
        float b2 = bias[16 * (mf0 + m) + 4 * lh + 2];
        float b3 = bias[16 * (mf0 + m) + 4 * lh + 3];
#pragma unroll
        for (int s = 0; s < 4; ++s) acc[m][s] = (f32x4){b0, b1, b2, b3};
    }

    const float* colbase = in + (size_t)b * C_ * N_ + n0;
    const int cq = t >> 6;

    for (int k = 0; k < 8; ++k) {
        const int c0 = k * 32;
        __syncthreads();
#pragma unroll
        for (int p = 0; p < 2; ++p) {
            int cl = 16 * p + 4 * cq;
            float v0 = colbase[(size_t)(c0 + cl + 0) * N_ + lane];
            float v1 = colbase[(size_t)(c0 + cl + 1) * N_ + lane];
            float v2 = colbase[(size_t)(c0 + cl + 2) * N_ + lane];
            float v3 = colbase[(size_t)(c0 + cl + 3) * N_ + lane];
            u16 h0 = f2bf(v0), h1 = f2bf(v1), h2 = f2bf(v2), h3 = f2bf(v3);
            ushort4 hv = {h0, h1, h2, h3};
            ushort4 lv = {f2bf(v0 - bf2f(h0)), f2bf(v1 - bf2f(h1)),
                          f2bf(v2 - bf2f(h2)), f2bf(v3 - bf2f(h3))};
            *(ushort4*)&xh[lane * 40 + cl] = hv;
            *(ushort4*)&xl[lane * 40 + cl] = lv;
        }
        __syncthreads();

        bf16x8 wh[2], wl[2];
#pragma unroll
        for (int m = 0; m < 2; ++m) {
            const float* wp = wm + (size_t)(16 * (mf0 + m) + lq) * C_ + c0 + 8 * lh;
            float4 a = *(const float4*)wp;
            float4 bq = *(const float4*)(wp + 4);
            float wf[8] = {a.x, a.y, a.z, a.w, bq.x, bq.y, bq.z, bq.w};
#pragma unroll
            for (int j = 0; j < 8; ++j) {
                u16 h = f2bf(wf[j]);
                wh[m][j] = (short)h;
                wl[m][j] = (short)f2bf(wf[j] - bf2f(h));
            }
        }
#pragma unroll
        for (int s = 0; s < 4; ++s) {
            bf16x8 xhf = *(const bf16x8*)&xh[(16 * s + lq) * 40 + 8 * lh];
            bf16x8 xlf = *(const bf16x8*)&xl[(16 * s + lq) * 40 + 8 * lh];
#pragma unroll
            for (int m = 0; m < 2; ++m) {
                acc[m][s] = __builtin_amdgcn_mfma_f32_16x16x32_bf16(wh[m], xhf, acc[m][s], 0, 0, 0);
                acc[m][s] = __builtin_amdgcn_mfma_f32_16x16x32_bf16(wl[m], xhf, acc[m][s], 0, 0, 0);
                acc[m][s] = __builtin_amdgcn_mfma_f32_16x16x32_bf16(wh[m], xlf, acc[m][s], 0, 0, 0);
            }
        }
    }

    if (which < 2) {
        u16* oh = (which == 0 ? th_hi : ph_hi) + (size_t)b * N_ * CI_;
        u16* ol = (which == 0 ? th_lo : ph_lo) + (size_t)b * N_ * CI_;
#pragma unroll
        for (int m = 0; m < 2; ++m)
#pragma unroll
            for (int s = 0; s < 4; ++s) {
                ushort4 hv, lv;
                u16 h;
                h = f2bf(acc[m][s][0]); hv.x = h; lv.x = f2bf(acc[m][s][0] - bf2f(h));
                h = f2bf(acc[m][s][1]); hv.y = h; lv.y = f2bf(acc[m][s][1] - bf2f(h));
                h = f2bf(acc[m][s][2]); hv.z = h; lv.z = f2bf(acc[m][s][2] - bf2f(h));
                h = f2bf(acc[m][s][3]); hv.w = h; lv.w = f2bf(acc[m][s][3] - bf2f(h));
                size_t ofs = (size_t)(n0 + 16 * s + lq) * CI_ + 16 * (mf0 + m) + 4 * lh;
                *(ushort4*)(oh + ofs) = hv;
                *(ushort4*)(ol + ofs) = lv;
            }
    } else {
        u16* gb = gt + (size_t)b * CI_ * N_;
#pragma unroll
        for (int m = 0; m < 2; ++m)
#pragma unroll
            for (int s = 0; s < 4; ++s)
#pragma unroll
                for (int r = 0; r < 4; ++r)
                    gb[(size_t)(16 * (mf0 + m) + 4 * lh + r) * N_ + n0 + 16 * s + lq] =
                        f2bf(acc[m][s][r]);
    }
}

// ---------------------------------------------------------------------------
// Flash attention: swapped-operand MFMA, 32 q per wave, kv-split x4.
// grid (N/128, B, 4), block 256 (4 waves x 32 q).  LDS 48KB.
// S^T = mfma(K, Q): lane holds S(q=lq, kv=16tt+4lh+r) per q-subtile.
// P redistribution to PV B-operand layout via 8 __shfl (no LDS).
// PV: O^T = mfma(Vt_row, pf): lane holds O(q=lq, d=16j+4lh+r).
// Partials (unnormalized O bf16, m/l f32) merged by merge_kernel.
// ---------------------------------------------------------------------------
__global__ __launch_bounds__(256, 2) void attn_kernel(
    const u16* __restrict__ th_hi, const u16* __restrict__ th_lo,
    const u16* __restrict__ ph_hi, const u16* __restrict__ ph_lo,
    const u16* __restrict__ gt, u16* __restrict__ part, float* __restrict__ ml)
{
    __shared__ u16 Ksh[64 * 128];
    __shared__ u16 Ksl[64 * 128];
    __shared__ u16 Vt[128 * 64];

    const int n0 = blockIdx.x * 128, b = blockIdx.y, sp = blockIdx.z;
    const int t = threadIdx.x, wv = t >> 6, lane = t & 63;
    const int lq = lane & 15, lh = lane >> 4;
    const int par = lh & 1, flip = lh >> 1;
    const int q0w = n0 + wv * 32;

    bf16x8 qfh[2][4], qfl[2][4];
#pragma unroll
    for (int qs = 0; qs < 2; ++qs) {
        const u16* qph = th_hi + ((size_t)b * N_ + q0w + 16 * qs + lq) * D_ + 8 * lh;
        const u16* qpl = th_lo + ((size_t)b * N_ + q0w + 16 * qs + lq) * D_ + 8 * lh;
#pragma unroll
        for (int c = 0; c < 4; ++c) {
            qfh[qs][c] = *(const bf16x8*)(qph + 32 * c);
            qfl[qs][c] = *(const bf16x8*)(qpl + 32 * c);
        }
    }

    f32x4 Ot[2][8];
#pragma unroll
    for (int qs = 0; qs < 2; ++qs)
#pragma unroll
        for (int j = 0; j < 8; ++j) Ot[qs][j] = (f32x4){0.f, 0.f, 0.f, 0.f};
    float m_run[2] = {-INFINITY, -INFINITY};
    float l_run[2] = {0.f, 0.f};

    const u16* kbh = ph_hi + ((size_t)b * N_ + (size_t)sp * KVQ) * D_;
    const u16* kbl = ph_lo + ((size_t)b * N_ + (size_t)sp * KVQ) * D_;
    const u16* vb  = gt + (size_t)b * D_ * N_ + sp * KVQ;

    for (int kv0 = 0; kv0 < KVQ; kv0 += 64) {
        __syncthreads();
        {
            int r = t >> 4, d0 = (t & 15) * 8;
#pragma unroll
            for (int i = 0; i < 4; ++i) {
                int rr = r + 16 * i;
                int off = rr * 128 + (d0 ^ ((rr & 7) << 3));
                *(bf16x8*)&Ksh[off] = *(const bf16x8*)(kbh + (size_t)(kv0 + rr) * D_ + d0);
                *(bf16x8*)&Ksl[off] = *(const bf16x8*)(kbl + (size_t)(kv0 + rr) * D_ + d0);
            }
            int d = t >> 3, k8 = (t & 7) * 8;
#pragma unroll
            for (int i = 0; i < 4; ++i) {
                int dd = d + 32 * i;
                *(bf16x8*)&Vt[dd * 64 + (k8 ^ ((dd & 7) << 3))] =
                    *(const bf16x8*)(vb + (size_t)dd * N_ + kv0 + k8);
            }
        }
        __syncthreads();

        // ---- S^T = K Q^T (hi/lo 3-term), both q-subtiles per K-read ----
        f32x4 S[2][4];
#pragma unroll
        for (int qs = 0; qs < 2; ++qs)
#pragma unroll
            for (int tt = 0; tt < 4; ++tt) S[qs][tt] = (f32x4){0.f, 0.f, 0.f, 0.f};
#pragma unroll
        for (int c = 0; c < 4; ++c)
#pragma unroll
            for (int tt = 0; tt < 4; ++tt) {
                int row = 16 * tt + lq;
                int off = row * 128 + ((32 * c + 8 * lh) ^ ((row & 7) << 3));
                bf16x8 kh = *(const bf16x8*)&Ksh[off];
                bf16x8 kl = *(const bf16x8*)&Ksl[off];
#pragma unroll
                for (int qs = 0; qs < 2; ++qs) {
                    S[qs][tt] = __builtin_amdgcn_mfma_f32_16x16x32_bf16(kh, qfh[qs][c], S[qs][tt], 0, 0, 0);
                    S[qs][tt] = __builtin_amdgcn_mfma_f32_16x16x32_bf16(kh, qfl[qs][c], S[qs][tt], 0, 0, 0);
                    S[qs][tt] = __builtin_amdgcn_mfma_f32_16x16x32_bf16(kl, qfh[qs][c], S[qs][tt], 0, 0, 0);
                }
            }

        // ---- softmax + P redistribution (register-only, per q-subtile) ----
        bf16x8 pf[2][2];
#pragma unroll
        for (int qs = 0; qs < 2; ++qs) {
            float mx = -INFINITY;
#pragma unroll
            for (int tt = 0; tt < 4; ++tt)
#pragma unroll
                for (int r = 0; r < 4; ++r) mx = fmaxf(mx, S[qs][tt][r]);
            mx = fmaxf(mx, __shfl_xor(mx, 16));
            mx = fmaxf(mx, __shfl_xor(mx, 32));
            float mn = fmaxf(m_run[qs], mx);
            float al = __expf(m_run[qs] - mn);
            m_run[qs] = mn;
            float p[4][4];
            float ls = 0.f;
#pragma unroll
            for (int tt = 0; tt < 4; ++tt)
#pragma unroll
                for (int r = 0; r < 4; ++r) {
                    p[tt][r] = __expf(S[qs][tt][r] - mn);
                    ls += p[tt][r];
                }
            ls += __shfl_xor(ls, 16);
            ls += __shfl_xor(ls, 32);
            l_run[qs] = l_run[qs] * al + ls;
#pragma unroll
            for (int j = 0; j < 8; ++j) Ot[qs][j] *= al;

            // pack own bf16 pairs: wloc[2tt+(r>>1)] covers kv = 16tt+4lh+2(r>>1)+{0,1}
            unsigned wloc[8];
#pragma unroll
            for (int tt = 0; tt < 4; ++tt) {
                wloc[2 * tt]     = pack2(p[tt][0], p[tt][1]);
                wloc[2 * tt + 1] = pack2(p[tt][2], p[tt][3]);
            }
            // 8 exchange ops within the 4-lane group {lq, lq+16, lq+32, lq+48}
            unsigned rcv[8];
#pragma unroll
            for (int k = 0; k < 8; ++k) {
                const int idx = k & 3;
                const int wL = ((idx >> 1) << 2) | (idx & 1);   // L = {0,1,4,5}
                unsigned snd = (par ^ (k >> 2)) ? wloc[wL + 2] : wloc[wL];
                int srcl = lq + 32 * par + 16 * ((k >> 2) ^ flip);
                rcv[k] = (unsigned)__shfl((int)snd, srcl);
            }
            // out[cc][u] = P pairs at kv = 32cc + 8lh + 2u (+1)
#pragma unroll
            for (int cc = 0; cc < 2; ++cc) {
                union { unsigned w[4]; bf16x8 v; } pu;
#pragma unroll
                for (int u = 0; u < 4; ++u) {
                    unsigned a  = rcv[4 * (u >> 1)       + 2 * cc + (u & 1)];
                    unsigned bb = rcv[4 * (1 - (u >> 1)) + 2 * cc + (u & 1)];
                    pu.w[u] = flip ? bb : a;
                }
                pf[qs][cc] = pu.v;
            }
        }

        // ---- O^T += V^T P^T : one V-read feeds both q-subtiles ----
#pragma unroll
        for (int cc = 0; cc < 2; ++cc)
#pragma unroll
            for (int j = 0; j < 8; ++j) {
                int row = 16 * j + lq;
                bf16x8 vf = *(const bf16x8*)&Vt[row * 64 + ((32 * cc + 8 * lh) ^ ((row & 7) << 3))];
                Ot[0][j] = __builtin_amdgcn_mfma_f32_16x16x32_bf16(vf, pf[0][cc], Ot[0][j], 0, 0, 0);
                Ot[1][j] = __builtin_amdgcn_mfma_f32_16x16x32_bf16(vf, pf[1][cc], Ot[1][j], 0, 0, 0);
            }
    }

    // ---- partial store: part[sp][b][q][d] bf16, ml[sp][b][q] = {m,l} ----
#pragma unroll
    for (int qs = 0; qs < 2; ++qs) {
        u16* pb = part + (((size_t)sp * B_ + b) * N_ + q0w + 16 * qs + lq) * D_;
#pragma unroll
        for (int j = 0; j < 8; ++j) {
            ushort4 pk = {f2bf(Ot[qs][j][0]), f2bf(Ot[qs][j][1]),
                          f2bf(Ot[qs][j][2]), f2bf(Ot[qs][j][3])};
            *(ushort4*)(pb + 16 * j + 4 * lh) = pk;
        }
        if (lh == 0) {
            float* mp = ml + ((((size_t)sp * B_ + b) * N_) + q0w + 16 * qs + lq) * 2;
            mp[0] = m_run[qs];
            mp[1] = l_run[qs];
        }
    }
}

// ---------------------------------------------------------------------------
// Merge 4 kv-split partials -> y[b][n][ci] bf16.  grid (N/64, B), block 256.
// ---------------------------------------------------------------------------
__global__ __launch_bounds__(256) void merge_kernel(
    const u16* __restrict__ part, const float* __restrict__ ml,
    u16* __restrict__ y)
{
    const int n0 = blockIdx.x * 64, b = blockIdx.y;
    const int t = threadIdx.x;
#pragma unroll
    for (int i = 0; i < 4; ++i) {
        int item = i * 256 + t;
        int q = n0 + (item >> 4), s8 = (item & 15) * 8;
        float2 mls[KVSPLIT];
        float m = -INFINITY;
#pragma unroll
        for (int s = 0; s < KVSPLIT; ++s) {
            mls[s] = *(const float2*)(ml + (((size_t)s * B_ + b) * N_ + q) * 2);
            m = fmaxf(m, mls[s].x);
        }
        float w[KVSPLIT];
        float denom = 0.f;
#pragma unroll
        for (int s = 0; s < KVSPLIT; ++s) {
            w[s] = __expf(mls[s].x - m);
            denom += w[s] * mls[s].y;
        }
        float inv = 1.f / denom;
        float acc[8];
#pragma unroll
        for (int e = 0; e < 8; ++e) acc[e] = 0.f;
#pragma unroll
        for (int s = 0; s < KVSPLIT; ++s) {
            bf16x8 o = *(const bf16x8*)(part + (((size_t)s * B_ + b) * N_ + q) * D_ + s8);
#pragma unroll
            for (int e = 0; e < 8; ++e) acc[e] += w[s] * bf2f((u16)o[e]);
        }
        bf16x8 ov;
#pragma unroll
        for (int e = 0; e < 8; ++e) ov[e] = (short)f2bf(acc[e] * inv);
        *(bf16x8*)(y + ((size_t)b * N_ + q) * CI_ + s8) = ov;
    }
}

// ---------------------------------------------------------------------------
// Wz conv1x1 (MFMA) + BN partial sums.  (unchanged from round 4)
// ---------------------------------------------------------------------------
__global__ __launch_bounds__(256) void wz_kernel(
    const u16* __restrict__ y, const float* __restrict__ wz_w,
    const float* __restrict__ wz_b, float* __restrict__ w_y,
    float* __restrict__ sums)
{
    __shared__ u16 ylds[64 * 128];
    const int n0 = blockIdx.x * 64, b = blockIdx.y;
    const int t = threadIdx.x, lane = t & 63, wv = t >> 6;
    const int lq = lane & 15, lh = lane >> 4;

#pragma unroll
    for (int i = 0; i < 4; ++i) {
        int flat = i * 256 + t;
        int row = flat >> 4, s = flat & 15;
        bf16x8 v = *(const bf16x8*)(y + ((size_t)(b * N_ + n0 + row)) * CI_ + 8 * s);
        *(bf16x8*)&ylds[row * 128 + 8 * (s ^ (row & 7))] = v;
    }
    __syncthreads();

    f32x4 acc[4][4];
#pragma unroll
    for (int mm = 0; mm < 4; ++mm) {
        float b0 = wz_b[16 * (4 * wv + mm) + 4 * lh + 0];
        float b1 = wz_b[16 * (4 * wv + mm) + 4 * lh + 1];
        float b2 = wz_b[16 * (4 * wv + mm) + 4 * lh + 2];
        float b3 = wz_b[16 * (4 * wv + mm) + 4 * lh + 3];
#pragma unroll
        for (int s = 0; s < 4; ++s) acc[mm][s] = (f32x4){b0, b1, b2, b3};
    }

#pragma unroll
    for (int k = 0; k < 4; ++k) {
        bf16x8 wf[4];
#pragma unroll
        for (int mm = 0; mm < 4; ++mm) {
            const float* wp = wz_w + (size_t)(16 * (4 * wv + mm) + lq) * CI_ + 32 * k + 8 * lh;
            float4 a = *(const float4*)wp;
            float4 bq = *(const float4*)(wp + 4);
            wf[mm][0] = (short)f2bf(a.x);  wf[mm][1] = (short)f2bf(a.y);
            wf[mm][2] = (short)f2bf(a.z);  wf[mm][3] = (short)f2bf(a.w);
            wf[mm][4] = (short)f2bf(bq.x); wf[mm][5] = (short)f2bf(bq.y);
            wf[mm][6] = (short)f2bf(bq.z); wf[mm][7] = (short)f2bf(bq.w);
        }
#pragma unroll
        for (int s = 0; s < 4; ++s) {
            int row = 16 * s + lq;
            bf16x8 yf = *(const bf16x8*)&ylds[row * 128 + 8 * ((4 * k + lh) ^ (row & 7))];
#pragma unroll
            for (int mm = 0; mm < 4; ++mm)
                acc[mm][s] = __builtin_amdgcn_mfma_f32_16x16x32_bf16(wf[mm], yf, acc[mm][s], 0, 0, 0);
        }
    }

#pragma unroll
    for (int mm = 0; mm < 4; ++mm) {
        int cb = 16 * (4 * wv + mm) + 4 * lh;
#pragma unroll
        for (int s = 0; s < 4; ++s) {
            int n = n0 + 16 * s + lq;
#pragma unroll
            for (int r = 0; r < 4; ++r)
                w_y[((size_t)b * C_ + cb + r) * N_ + n] = acc[mm][s][r];
        }
#pragma unroll
        for (int r = 0; r < 4; ++r) {
            float sv = acc[mm][0][r] + acc[mm][1][r] + acc[mm][2][r] + acc[mm][3][r];
            float qv = acc[mm][0][r] * acc[mm][0][r] + acc[mm][1][r] * acc[mm][1][r]
                     + acc[mm][2][r] * acc[mm][2][r] + acc[mm][3][r] * acc[mm][3][r];
#pragma unroll
            for (int d = 1; d < 16; d <<= 1) {
                sv += __shfl_xor(sv, d);
                qv += __shfl_xor(qv, d);
            }
            if (lq == 0) {
                atomicAdd(&sums[cb + r], sv);
                atomicAdd(&sums[C_ + cb + r], qv);
            }
        }
    }
}

// ---------------------------------------------------------------------------
// BN finalize + residual  (unchanged)
// ---------------------------------------------------------------------------
__global__ __launch_bounds__(256) void final_kernel(
    const float* __restrict__ w_y, const float* __restrict__ src,
    const float* __restrict__ gamma, const float* __restrict__ beta,
    const float* __restrict__ sums, float* __restrict__ out)
{
    const float invN = 1.0f / (float)(B_ * N_);
    const size_t tot4 = (size_t)B_ * C_ * N_ / 4;
    size_t stride = (size_t)gridDim.x * blockDim.x;
    for (size_t i4 = (size_t)blockIdx.x * blockDim.x + threadIdx.x; i4 < tot4; i4 += stride) {
        size_t i = i4 * 4;
        int c = (int)((i / N_) % C_);
        float mean  = sums[c] * invN;
        float var   = sums[C_ + c] * invN - mean * mean;
        float scale = rsqrtf(var + 1e-5f) * gamma[c];
        float bb    = beta[c];
        float4 w = *(const float4*)(w_y + i);
        float4 s = *(const float4*)(src + i);
        float4 o;
        o.x = (w.x - mean) * scale + bb + s.x;
        o.y = (w.y - mean) * scale + bb + s.y;
        o.z = (w.z - mean) * scale + bb + s.z;
        o.w = (w.w - mean) * scale + bb + s.w;
        *(float4*)((float*)out + i) = o;
    }
}

extern "C" void kernel_launch(void* const* d_in, const int* in_sizes, int n_in,
                              void* d_out, int out_size, void* d_ws, size_t ws_size,
                              hipStream_t stream)
{
    const float* x     = (const float*)d_in[0];
    const float* src   = (const float*)d_in[1];
    const float* g_w   = (const float*)d_in[2];
    const float* g_b   = (const float*)d_in[3];
    const float* th_w  = (const float*)d_in[4];
    const float* th_b  = (const float*)d_in[5];
    const float* ph_w  = (const float*)d_in[6];
    const float* ph_b  = (const float*)d_in[7];
    const float* wz_w  = (const float*)d_in[8];
    const float* wz_b  = (const float*)d_in[9];
    const float* gamma = (const float*)d_in[10];
    const float* beta  = (const float*)d_in[11];

    char* ws = (char*)d_ws;
    u16*   th_hi = (u16*)(ws + (0u  << 20));    //  4 MB
    u16*   th_lo = (u16*)(ws + (4u  << 20));    //  4 MB
    u16*   ph_hi = (u16*)(ws + (8u  << 20));    //  4 MB
    u16*   ph_lo = (u16*)(ws + (12u << 20));    //  4 MB
    u16*   gt    = (u16*)(ws + (16u << 20));    //  4 MB
    u16*   part  = (u16*)(ws + (20u << 20));    // 16 MB [4][B][N][D] bf16
    float* mlbuf = (float*)(ws + (36u << 20));  // 512 KB [4][B][N][2]
    u16*   y     = (u16*)(ws + (0u  << 20));    //  4 MB, aliases th_hi (dead)
    float* w_y   = (float*)(ws + (20u << 20));  // 16 MB, aliases part (dead)
    float* sums  = (float*)(ws + (36u << 20) + (1u << 19)); // 2 KB

    hipMemsetAsync(sums, 0, 2 * C_ * sizeof(float), stream);

    embed_kernel<<<dim3(64, 4, 3), 256, 0, stream>>>(
        x, src, g_w, g_b, th_w, th_b, ph_w, ph_b,
        th_hi, th_lo, ph_hi, ph_lo, gt);
    attn_kernel<<<dim3(N_ / 128, B_, KVSPLIT), 256, 0, stream>>>(
        th_hi, th_lo, ph_hi, ph_lo, gt, part, mlbuf);
    merge_kernel<<<dim3(64, 4), 256, 0, stream>>>(part, mlbuf, y);
    wz_kernel<<<dim3(64, 4), 256, 0, stream>>>(y, wz_w, wz_b, w_y, sums);
    final_kernel<<<2048, 256, 0, stream>>>(w_y, src, gamma, beta, sums, (float*)d_out);
}

// Round 8
// 163.732 us; speedup vs baseline: 1.1940x; 1.1924x over previous
//
#include <hip/hip_runtime.h>
#include <math.h>

#define B_  4
#define C_  256
#define CI_ 128
#define N_  4096
#define D_  128
#define KVSPLIT 4
#define KVQ  (N_ / KVSPLIT)
#define KVT  64
#define NT   (KVQ / KVT)

typedef _Float16 f16;
typedef f16 f16x8 __attribute__((ext_vector_type(8)));
typedef float f32x4 __attribute__((ext_vector_type(4)));
typedef unsigned short u16;

__device__ __forceinline__ u16 f2h(float x) {
    union { f16 h; u16 u; } v; v.h = (f16)x; return v.u;
}
__device__ __forceinline__ unsigned packh2(float a, float b) {
    union { f16 h[2]; unsigned u; } v; v.h[0] = (f16)a; v.h[1] = (f16)b; return v.u;
}

__device__ __forceinline__ void gll16(const void* g, void* l) {
    __builtin_amdgcn_global_load_lds(
        (const __attribute__((address_space(1))) void*)g,
        (__attribute__((address_space(3))) void*)l, 16, 0, 0);
}

// ---------------------------------------------------------------------------
// Embedding conv1x1, f16 single-term MFMA.
// grid (N/64, B, 2), block 256.
// which 0: theta(x) -> th[n][ci]; which 1: phi(src)->ph[n][ci] AND g(src)->gt[ci][n]
// ---------------------------------------------------------------------------
__global__ __launch_bounds__(256) void embed_kernel(
    const float* __restrict__ x, const float* __restrict__ src,
    const float* __restrict__ g_w, const float* __restrict__ g_b,
    const float* __restrict__ th_w, const float* __restrict__ th_b,
    const float* __restrict__ ph_w, const float* __restrict__ ph_b,
    u16* __restrict__ th, u16* __restrict__ ph, u16* __restrict__ gt)
{
    __shared__ u16 xh[64 * 40];          // input tile transposed, f16, stride 40

    const int n0 = blockIdx.x * 64, b = blockIdx.y, which = blockIdx.z;
    const float* in   = which ? src  : x;
    const float* wm   = which ? ph_w : th_w;
    const float* bias = which ? ph_b : th_b;

    const int t = threadIdx.x, lane = t & 63, wv = t >> 6;
    const int lq = lane & 15, lh = lane >> 4;
    const int mf0 = wv * 2, cq = t >> 6;

    f32x4 accp[2][4], accg[2][4];
#pragma unroll
    for (int m = 0; m < 2; ++m) {
        float b0 = bias[16 * (mf0 + m) + 4 * lh + 0];
        float b1 = bias[16 * (mf0 + m) + 4 * lh + 1];
        float b2 = bias[16 * (mf0 + m) + 4 * lh + 2];
        float b3 = bias[16 * (mf0 + m) + 4 * lh + 3];
#pragma unroll
        for (int s = 0; s < 4; ++s) accp[m][s] = (f32x4){b0, b1, b2, b3};
        if (which) {
            float g0 = g_b[16 * (mf0 + m) + 4 * lh + 0];
            float g1 = g_b[16 * (mf0 + m) + 4 * lh + 1];
            float g2 = g_b[16 * (mf0 + m) + 4 * lh + 2];
            float g3 = g_b[16 * (mf0 + m) + 4 * lh + 3];
#pragma unroll
            for (int s = 0; s < 4; ++s) accg[m][s] = (f32x4){g0, g1, g2, g3};
        }
    }

    const float* colbase = in + (size_t)b * C_ * N_ + n0;

    for (int k = 0; k < 8; ++k) {
        const int c0 = k * 32;
        __syncthreads();
#pragma unroll
        for (int p = 0; p < 2; ++p) {
            int cl = 16 * p + 4 * cq;
            float v0 = colbase[(size_t)(c0 + cl + 0) * N_ + lane];
            float v1 = colbase[(size_t)(c0 + cl + 1) * N_ + lane];
            float v2 = colbase[(size_t)(c0 + cl + 2) * N_ + lane];
            float v3 = colbase[(size_t)(c0 + cl + 3) * N_ + lane];
            union { f16 h[4]; ushort4 u; } cv;
            cv.h[0] = (f16)v0; cv.h[1] = (f16)v1; cv.h[2] = (f16)v2; cv.h[3] = (f16)v3;
            *(ushort4*)&xh[lane * 40 + cl] = cv.u;
        }
        __syncthreads();

        f16x8 wfp[2], wfg[2];
#pragma unroll
        for (int m = 0; m < 2; ++m) {
            const float* wp = wm + (size_t)(16 * (mf0 + m) + lq) * C_ + c0 + 8 * lh;
            float4 a = *(const float4*)wp;
            float4 bq = *(const float4*)(wp + 4);
            wfp[m][0] = (f16)a.x;  wfp[m][1] = (f16)a.y;
            wfp[m][2] = (f16)a.z;  wfp[m][3] = (f16)a.w;
            wfp[m][4] = (f16)bq.x; wfp[m][5] = (f16)bq.y;
            wfp[m][6] = (f16)bq.z; wfp[m][7] = (f16)bq.w;
            if (which) {
                const float* wg = g_w + (size_t)(16 * (mf0 + m) + lq) * C_ + c0 + 8 * lh;
                float4 ga = *(const float4*)wg;
                float4 gq = *(const float4*)(wg + 4);
                wfg[m][0] = (f16)ga.x;  wfg[m][1] = (f16)ga.y;
                wfg[m][2] = (f16)ga.z;  wfg[m][3] = (f16)ga.w;
                wfg[m][4] = (f16)gq.x;  wfg[m][5] = (f16)gq.y;
                wfg[m][6] = (f16)gq.z;  wfg[m][7] = (f16)gq.w;
            }
        }
#pragma unroll
        for (int s = 0; s < 4; ++s) {
            f16x8 xf = *(const f16x8*)&xh[(16 * s + lq) * 40 + 8 * lh];
#pragma unroll
            for (int m = 0; m < 2; ++m) {
                accp[m][s] = __builtin_amdgcn_mfma_f32_16x16x32_f16(wfp[m], xf, accp[m][s], 0, 0, 0);
                if (which)
                    accg[m][s] = __builtin_amdgcn_mfma_f32_16x16x32_f16(wfg[m], xf, accg[m][s], 0, 0, 0);
            }
        }
    }

    // epilogue. D-layout: col(n)=lq, row(ci)=16*mf+4*lh+reg
    u16* op = (which ? ph : th) + (size_t)b * N_ * CI_;
#pragma unroll
    for (int m = 0; m < 2; ++m)
#pragma unroll
        for (int s = 0; s < 4; ++s) {
            ushort4 pk = {f2h(accp[m][s][0]), f2h(accp[m][s][1]),
                          f2h(accp[m][s][2]), f2h(accp[m][s][3])};
            *(ushort4*)(op + (size_t)(n0 + 16 * s + lq) * CI_ + 16 * (mf0 + m) + 4 * lh) = pk;
        }
    if (which) {
        u16* gb2 = gt + (size_t)b * CI_ * N_;
#pragma unroll
        for (int m = 0; m < 2; ++m)
#pragma unroll
            for (int s = 0; s < 4; ++s)
#pragma unroll
                for (int r = 0; r < 4; ++r)
                    gb2[(size_t)(16 * (mf0 + m) + 4 * lh + r) * N_ + n0 + 16 * s + lq] =
                        f2h(accg[m][s][r]);
    }
}

// ---------------------------------------------------------------------------
// Flash attention, f16 single-term MFMA, global_load_lds double-buffered.
// grid (N/128, B, KVSPLIT), block 256 (4 waves x 32 q).  LDS 64KB (2 bufs).
// S^T = mfma(K, Q): lane holds S(q=lq, kv=16tt+4lh+r) per q-subtile.
// P redistribution via 8 __shfl (register-only).  PV: O^T = mfma(Vt_row, pf).
// Staging: gll with pre-swizzled GLOBAL source; LDS dest linear.
//   K:  LDS[rr][slot] = K[rr][slot ^ (rr&7)]   (slot = 8-halfword unit)
//   Vt: LDS[dd][slot] = V^T[dd][kv0 + 8*(slot ^ (dd&7))]
// K tile = 64x128 f16 = 16KB = 16 gll; V tile = 128x64 f16 = 16KB = 16 gll.
// ---------------------------------------------------------------------------
__global__ __launch_bounds__(256) void attn_kernel(
    const u16* __restrict__ th, const u16* __restrict__ ph,
    const u16* __restrict__ gt, u16* __restrict__ part, float* __restrict__ ml)
{
    __shared__ u16 Ks[2][KVT * 128];
    __shared__ u16 Vt[2][128 * KVT];

    const int n0 = blockIdx.x * 128, b = blockIdx.y, sp = blockIdx.z;
    const int t = threadIdx.x, wv = t >> 6, lane = t & 63;
    const int lq = lane & 15, lh = lane >> 4;
    const int par = lh & 1, flip = lh >> 1;
    const int q0w = n0 + wv * 32;

    const u16* kb = ph + ((size_t)b * N_ + (size_t)sp * KVQ) * D_;
    const u16* vb = gt + (size_t)b * D_ * N_ + sp * KVQ;

    // Q fragments (f16, register resident)
    f16x8 qf[2][4];
#pragma unroll
    for (int qs = 0; qs < 2; ++qs) {
        const u16* qp = th + ((size_t)b * N_ + q0w + 16 * qs + lq) * D_ + 8 * lh;
#pragma unroll
        for (int c = 0; c < 4; ++c) qf[qs][c] = *(const f16x8*)(qp + 32 * c);
    }

    f32x4 Ot[2][8];
#pragma unroll
    for (int qs = 0; qs < 2; ++qs)
#pragma unroll
        for (int j = 0; j < 8; ++j) Ot[qs][j] = (f32x4){0.f, 0.f, 0.f, 0.f};
    float m_run[2] = {-INFINITY, -INFINITY};
    float l_run[2] = {0.f, 0.f};

    // ---- async staging: K 16KB (16 gll) + V 16KB (16 gll), 8 gll/wave ----
    auto stage = [&](int buf, int it) {
        const int kv0 = it * KVT;
#pragma unroll
        for (int ii = 0; ii < 4; ++ii) {
            int i = 4 * wv + ii;                    // 0..15
            int rr = 4 * i + (lane >> 4);           // kv row 0..63
            const u16* g = kb + (size_t)(kv0 + rr) * D_ + (((lane & 15) ^ (rr & 7)) * 8);
            gll16(g, &Ks[buf][i * 512]);
        }
#pragma unroll
        for (int jj = 0; jj < 4; ++jj) {
            int j = 4 * wv + jj;                    // 0..15
            int dd = 8 * j + (lane >> 3);           // d row 0..127
            const u16* g = vb + (size_t)dd * N_ + kv0 + ((lane & 7) ^ (dd & 7)) * 8;
            gll16(g, &Vt[buf][j * 512]);
        }
    };

    stage(0, 0);
    for (int it = 0; it < NT; ++it) {
        __syncthreads();                       // drains vmcnt -> buf[it&1] ready
        if (it + 1 < NT) stage((it + 1) & 1, it + 1);   // overlaps compute below
        const u16* K = Ks[it & 1];
        const u16* V = Vt[it & 1];

        // ---- S^T = K Q^T : lane holds S(q=lq, kv=16tt+4lh+r) ----
        f32x4 S[2][4];
#pragma unroll
        for (int qs = 0; qs < 2; ++qs)
#pragma unroll
            for (int tt = 0; tt < 4; ++tt) S[qs][tt] = (f32x4){0.f, 0.f, 0.f, 0.f};
#pragma unroll
        for (int c = 0; c < 4; ++c)
#pragma unroll
            for (int tt = 0; tt < 4; ++tt) {
                int row = 16 * tt + lq;
                f16x8 kf = *(const f16x8*)&K[row * 128 + ((32 * c + 8 * lh) ^ ((row & 7) << 3))];
                S[0][tt] = __builtin_amdgcn_mfma_f32_16x16x32_f16(kf, qf[0][c], S[0][tt], 0, 0, 0);
                S[1][tt] = __builtin_amdgcn_mfma_f32_16x16x32_f16(kf, qf[1][c], S[1][tt], 0, 0, 0);
            }

        // ---- per-lane online softmax + register P redistribution ----
        f16x8 pf[2][2];
#pragma unroll
        for (int qs = 0; qs < 2; ++qs) {
            float mx = -INFINITY;
#pragma unroll
            for (int tt = 0; tt < 4; ++tt)
#pragma unroll
                for (int r = 0; r < 4; ++r) mx = fmaxf(mx, S[qs][tt][r]);
            mx = fmaxf(mx, __shfl_xor(mx, 16));
            mx = fmaxf(mx, __shfl_xor(mx, 32));
            float mn = fmaxf(m_run[qs], mx);
            float al = __expf(m_run[qs] - mn);
            m_run[qs] = mn;
            float p[4][4];
            float ls = 0.f;
#pragma unroll
            for (int tt = 0; tt < 4; ++tt)
#pragma unroll
                for (int r = 0; r < 4; ++r) {
                    p[tt][r] = __expf(S[qs][tt][r] - mn);
                    ls += p[tt][r];
                }
            ls += __shfl_xor(ls, 16);
            ls += __shfl_xor(ls, 32);
            l_run[qs] = l_run[qs] * al + ls;
#pragma unroll
            for (int j = 0; j < 8; ++j) Ot[qs][j] *= al;

            unsigned wloc[8];
#pragma unroll
            for (int tt = 0; tt < 4; ++tt) {
                wloc[2 * tt]     = packh2(p[tt][0], p[tt][1]);
                wloc[2 * tt + 1] = packh2(p[tt][2], p[tt][3]);
            }
            unsigned rcv[8];
#pragma unroll
            for (int k = 0; k < 8; ++k) {
                const int idx = k & 3;
                const int wL = ((idx >> 1) << 2) | (idx & 1);
                unsigned snd = (par ^ (k >> 2)) ? wloc[wL + 2] : wloc[wL];
                int srcl = lq + 32 * par + 16 * ((k >> 2) ^ flip);
                rcv[k] = (unsigned)__shfl((int)snd, srcl);
            }
#pragma unroll
            for (int cc = 0; cc < 2; ++cc) {
                union { unsigned w[4]; f16x8 v; } pu;
#pragma unroll
                for (int u = 0; u < 4; ++u) {
                    unsigned a  = rcv[4 * (u >> 1)       + 2 * cc + (u & 1)];
                    unsigned bb = rcv[4 * (1 - (u >> 1)) + 2 * cc + (u & 1)];
                    pu.w[u] = flip ? bb : a;
                }
                pf[qs][cc] = pu.v;
            }
        }

        // ---- O^T += V^T P^T : one V-read feeds both q-subtiles ----
#pragma unroll
        for (int cc = 0; cc < 2; ++cc)
#pragma unroll
            for (int j = 0; j < 8; ++j) {
                int row = 16 * j + lq;
                f16x8 vf = *(const f16x8*)&V[row * 64 + ((32 * cc + 8 * lh) ^ ((row & 7) << 3))];
                Ot[0][j] = __builtin_amdgcn_mfma_f32_16x16x32_f16(vf, pf[0][cc], Ot[0][j], 0, 0, 0);
                Ot[1][j] = __builtin_amdgcn_mfma_f32_16x16x32_f16(vf, pf[1][cc], Ot[1][j], 0, 0, 0);
            }
    }

    // ---- partial store: part[sp][b][q][d] f16, ml[sp][b][q] = {m,l} ----
#pragma unroll
    for (int qs = 0; qs < 2; ++qs) {
        u16* pb = part + (((size_t)sp * B_ + b) * N_ + q0w + 16 * qs + lq) * D_;
#pragma unroll
        for (int j = 0; j < 8; ++j) {
            ushort4 pk = {f2h(Ot[qs][j][0]), f2h(Ot[qs][j][1]),
                          f2h(Ot[qs][j][2]), f2h(Ot[qs][j][3])};
            *(ushort4*)(pb + 16 * j + 4 * lh) = pk;
        }
        if (lh == 0) {
            float* mp = ml + (((size_t)sp * B_ + b) * N_ + q0w + 16 * qs + lq) * 2;
            mp[0] = m_run[qs];
            mp[1] = l_run[qs];
        }
    }
}

// ---------------------------------------------------------------------------
// Fused merge + Wz conv1x1 (f16 MFMA) + BN partial sums.
// grid (N/64, B), block 256.  Merges KVSPLIT partials while staging ylds.
// ---------------------------------------------------------------------------
__global__ __launch_bounds__(256) void wz_kernel(
    const u16* __restrict__ part, const float* __restrict__ ml,
    const float* __restrict__ wz_w, const float* __restrict__ wz_b,
    u16* __restrict__ w_y, float* __restrict__ sums)
{
    __shared__ u16 ylds[64 * 128];
    const int n0 = blockIdx.x * 64, b = blockIdx.y;
    const int t = threadIdx.x, lane = t & 63, wv = t >> 6;
    const int lq = lane & 15, lh = lane >> 4;

#pragma unroll
    for (int i = 0; i < 4; ++i) {
        int flat = i * 256 + t;
        int row = flat >> 4, s = flat & 15;
        int q = n0 + row;
        float2 mls[KVSPLIT];
        float m = -INFINITY;
#pragma unroll
        for (int sp = 0; sp < KVSPLIT; ++sp) {
            mls[sp] = *(const float2*)(ml + (((size_t)sp * B_ + b) * N_ + q) * 2);
            m = fmaxf(m, mls[sp].x);
        }
        float wts[KVSPLIT], denom = 0.f;
#pragma unroll
        for (int sp = 0; sp < KVSPLIT; ++sp) {
            wts[sp] = __expf(mls[sp].x - m);
            denom += wts[sp] * mls[sp].y;
        }
        float inv = 1.f / denom;
        float acc8[8];
#pragma unroll
        for (int e = 0; e < 8; ++e) acc8[e] = 0.f;
#pragma unroll
        for (int sp = 0; sp < KVSPLIT; ++sp) {
            f16x8 o = *(const f16x8*)(part + (((size_t)sp * B_ + b) * N_ + q) * D_ + 8 * s);
#pragma unroll
            for (int e = 0; e < 8; ++e) acc8[e] += wts[sp] * (float)o[e];
        }
        union { f16 h[8]; f16x8 v; } mv;
#pragma unroll
        for (int e = 0; e < 8; ++e) mv.h[e] = (f16)(acc8[e] * inv);
        *(f16x8*)&ylds[row * 128 + 8 * (s ^ (row & 7))] = mv.v;
    }
    __syncthreads();

    f32x4 acc[4][4];
#pragma unroll
    for (int mm = 0; mm < 4; ++mm) {
        float b0 = wz_b[16 * (4 * wv + mm) + 4 * lh + 0];
        float b1 = wz_b[16 * (4 * wv + mm) + 4 * lh + 1];
        float b2 = wz_b[16 * (4 * wv + mm) + 4 * lh + 2];
        float b3 = wz_b[16 * (4 * wv + mm) + 4 * lh + 3];
#pragma unroll
        for (int s = 0; s < 4; ++s) acc[mm][s] = (f32x4){b0, b1, b2, b3};
    }

#pragma unroll
    for (int k = 0; k < 4; ++k) {
        f16x8 wf[4];
#pragma unroll
        for (int mm = 0; mm < 4; ++mm) {
            const float* wp = wz_w + (size_t)(16 * (4 * wv + mm) + lq) * CI_ + 32 * k + 8 * lh;
            float4 a = *(const float4*)wp;
            float4 bq = *(const float4*)(wp + 4);
            wf[mm][0] = (f16)a.x;  wf[mm][1] = (f16)a.y;
            wf[mm][2] = (f16)a.z;  wf[mm][3] = (f16)a.w;
            wf[mm][4] = (f16)bq.x; wf[mm][5] = (f16)bq.y;
            wf[mm][6] = (f16)bq.z; wf[mm][7] = (f16)bq.w;
        }
#pragma unroll
        for (int s = 0; s < 4; ++s) {
            int row = 16 * s + lq;
            f16x8 yf = *(const f16x8*)&ylds[row * 128 + 8 * ((4 * k + lh) ^ (row & 7))];
#pragma unroll
            for (int mm = 0; mm < 4; ++mm)
                acc[mm][s] = __builtin_amdgcn_mfma_f32_16x16x32_f16(wf[mm], yf, acc[mm][s], 0, 0, 0);
        }
    }

#pragma unroll
    for (int mm = 0; mm < 4; ++mm) {
        int cb = 16 * (4 * wv + mm) + 4 * lh;
#pragma unroll
        for (int s = 0; s < 4; ++s) {
            int n = n0 + 16 * s + lq;
#pragma unroll
            for (int r = 0; r < 4; ++r)
                w_y[((size_t)b * C_ + cb + r) * N_ + n] = f2h(acc[mm][s][r]);
        }
#pragma unroll
        for (int r = 0; r < 4; ++r) {
            float sv = acc[mm][0][r] + acc[mm][1][r] + acc[mm][2][r] + acc[mm][3][r];
            float qv = acc[mm][0][r] * acc[mm][0][r] + acc[mm][1][r] * acc[mm][1][r]
                     + acc[mm][2][r] * acc[mm][2][r] + acc[mm][3][r] * acc[mm][3][r];
#pragma unroll
            for (int d = 1; d < 16; d <<= 1) {
                sv += __shfl_xor(sv, d);
                qv += __shfl_xor(qv, d);
            }
            if (lq == 0) {
                atomicAdd(&sums[cb + r], sv);
                atomicAdd(&sums[C_ + cb + r], qv);
            }
        }
    }
}

// ---------------------------------------------------------------------------
// BN finalize + residual (w_y is f16)
// ---------------------------------------------------------------------------
__global__ __launch_bounds__(256) void final_kernel(
    const u16* __restrict__ w_y, const float* __restrict__ src,
    const float* __restrict__ gamma, const float* __restrict__ beta,
    const float* __restrict__ sums, float* __restrict__ out)
{
    const float invN = 1.0f / (float)(B_ * N_);
    size_t i8 = ((size_t)blockIdx.x * blockDim.x + threadIdx.x) * 8;
    if (i8 >= (size_t)B_ * C_ * N_) return;
    int c = (int)((i8 / N_) % C_);
    float mean  = sums[c] * invN;
    float var   = sums[C_ + c] * invN - mean * mean;
    float scale = rsqrtf(var + 1e-5f) * gamma[c];
    float bb    = beta[c];
    f16x8 w = *(const f16x8*)(w_y + i8);
    float4 s0 = *(const float4*)(src + i8);
    float4 s1 = *(const float4*)(src + i8 + 4);
    float4 o0, o1;
    o0.x = ((float)w[0] - mean) * scale + bb + s0.x;
    o0.y = ((float)w[1] - mean) * scale + bb + s0.y;
    o0.z = ((float)w[2] - mean) * scale + bb + s0.z;
    o0.w = ((float)w[3] - mean) * scale + bb + s0.w;
    o1.x = ((float)w[4] - mean) * scale + bb + s1.x;
    o1.y = ((float)w[5] - mean) * scale + bb + s1.y;
    o1.z = ((float)w[6] - mean) * scale + bb + s1.z;
    o1.w = ((float)w[7] - mean) * scale + bb + s1.w;
    *(float4*)(out + i8)     = o0;
    *(float4*)(out + i8 + 4) = o1;
}

extern "C" void kernel_launch(void* const* d_in, const int* in_sizes, int n_in,
                              void* d_out, int out_size, void* d_ws, size_t ws_size,
                              hipStream_t stream)
{
    const float* x     = (const float*)d_in[0];
    const float* src   = (const float*)d_in[1];
    const float* g_w   = (const float*)d_in[2];
    const float* g_b   = (const float*)d_in[3];
    const float* th_w  = (const float*)d_in[4];
    const float* th_b  = (const float*)d_in[5];
    const float* ph_w  = (const float*)d_in[6];
    const float* ph_b  = (const float*)d_in[7];
    const float* wz_w  = (const float*)d_in[8];
    const float* wz_b  = (const float*)d_in[9];
    const float* gamma = (const float*)d_in[10];
    const float* beta  = (const float*)d_in[11];

    char* ws = (char*)d_ws;
    u16*   th    = (u16*)(ws + (0u  << 20));    //  4 MB (dead after attn)
    u16*   ph    = (u16*)(ws + (4u  << 20));    //  4 MB (dead after attn)
    u16*   gt    = (u16*)(ws + (8u  << 20));    //  4 MB (dead after attn)
    u16*   part  = (u16*)(ws + (12u << 20));    // 16 MB [KVSPLIT][B][N][D] f16
    float* mlbuf = (float*)(ws + (28u << 20));  // 512 KB
    u16*   w_y   = (u16*)(ws + (0u  << 20));    //  8 MB f16, aliases th+ph
    float* sums  = (float*)(ws + (28u << 20) + (1u << 19)); // 2 KB

    hipMemsetAsync(sums, 0, 2 * C_ * sizeof(float), stream);

    embed_kernel<<<dim3(64, 4, 2), 256, 0, stream>>>(
        x, src, g_w, g_b, th_w, th_b, ph_w, ph_b, th, ph, gt);
    attn_kernel<<<dim3(N_ / 128, B_, KVSPLIT), 256, 0, stream>>>(
        th, ph, gt, part, mlbuf);
    wz_kernel<<<dim3(64, 4), 256, 0, stream>>>(part, mlbuf, wz_w, wz_b, w_y, sums);
    final_kernel<<<2048, 256, 0, stream>>>(w_y, src, gamma, beta, sums, (float*)d_out);
}